// Round 2
// baseline (274.597 us; speedup 1.0000x reference)
//
#include <hip/hip_runtime.h>

#define SEQ   512
#define BATCH 4096
#define NT    16

template<int CTRL>
__device__ __forceinline__ float dppf(float x) {
    return __int_as_float(__builtin_amdgcn_update_dpp(0, __float_as_int(x), CTRL, 0xf, 0xf, true));
}
template<int CTRL>
__device__ __forceinline__ int dppi(int x) {
    return __builtin_amdgcn_update_dpp(0, x, CTRL, 0xf, 0xf, true);
}

// One 16-lane DPP row per batch element. lane = (b_local, tn).
__global__ __launch_bounds__(256, 1) void crf_fwd(
    const float* __restrict__ em,   // [S,B,T]
    const int*   __restrict__ tg,   // [S,B]
    const float* __restrict__ mk,   // [S,B]
    const float* __restrict__ st,   // [T]
    const float* __restrict__ en,   // [T]
    const float* __restrict__ tr,   // [T,T]
    float* __restrict__ out)        // [B]
{
    __shared__ float ltr[NT * NT];
    const int tid = threadIdx.x;
    ltr[tid] = tr[tid];            // blockDim == 256 == NT*NT
    __syncthreads();

    const int g    = blockIdx.x * 256 + tid;
    const int b    = g >> 4;
    const int tn   = g & 15;
    const int lane = tid & 63;

    // Runtime probe: does row_ror:1 deliver lane (i+1)&15's value, or (i-1)&15's?
    const int pv = dppi<0x121>(lane);
    const bool plus = (pv == ((lane & ~15) | ((lane + 1) & 15)));

    // Per-lane rotated column of E = exp(trans): e[k] pairs with ror^k(alpha).
    float e[16];
#pragma unroll
    for (int k = 0; k < 16; ++k) {
        const int tp = plus ? ((tn + k) & 15) : ((tn - k) & 15);
        e[k] = __expf(ltr[tp * NT + tn]);
    }
    const float et_raw = en[tn];
    const float e_end  = __expf(et_raw);
    const float st_raw = st[tn];

    const float* emp = em + b * NT + tn;
    const int*   tgp = tg + b;
    const float* mkp = mk + b;

    float peA[8], pmA[8], peB[8], pmB[8];
    int   ptA[8], ptB[8];

#define LOADC(s0, pe, pt, pm)                                   \
    { _Pragma("unroll")                                         \
      for (int j = 0; j < 8; ++j) {                             \
          pe[j] = emp[(s0 + j) * (BATCH * NT)];                 \
          pt[j] = tgp[(s0 + j) * BATCH];                        \
          pm[j] = mkp[(s0 + j) * BATCH];                        \
      } }

#define STEP(pe, pt, pm, j) {                                                        \
    const float emit = pe[j]; const int tag = pt[j]; const float m = pm[j];          \
    const float a1  = dppf<0x121>(alpha), a2  = dppf<0x122>(alpha);                  \
    const float a3  = dppf<0x123>(alpha), a4  = dppf<0x124>(alpha);                  \
    const float a5  = dppf<0x125>(alpha), a6  = dppf<0x126>(alpha);                  \
    const float a7  = dppf<0x127>(alpha), a8  = dppf<0x128>(alpha);                  \
    const float a9  = dppf<0x129>(alpha), a10 = dppf<0x12A>(alpha);                  \
    const float a11 = dppf<0x12B>(alpha), a12 = dppf<0x12C>(alpha);                  \
    const float a13 = dppf<0x12D>(alpha), a14 = dppf<0x12E>(alpha);                  \
    const float a15 = dppf<0x12F>(alpha);                                            \
    float w0 = fmaf(alpha, e[0],  a4  * e[4]);                                       \
    float w1 = fmaf(a1,    e[1],  a5  * e[5]);                                       \
    float w2 = fmaf(a2,    e[2],  a6  * e[6]);                                       \
    float w3 = fmaf(a3,    e[3],  a7  * e[7]);                                       \
    w0 = fmaf(a8,  e[8],  w0); w1 = fmaf(a9,  e[9],  w1);                            \
    w2 = fmaf(a10, e[10], w2); w3 = fmaf(a11, e[11], w3);                            \
    w0 = fmaf(a12, e[12], w0); w1 = fmaf(a13, e[13], w1);                            \
    w2 = fmaf(a14, e[14], w2); w3 = fmaf(a15, e[15], w3);                            \
    const float w = (w0 + w1) + (w2 + w3);                                           \
    float p = w * __expf(emit);                                                      \
    const bool upd = (m > 0.f);                                                      \
    p = upd ? p : alpha;                                                             \
    float r = fmaxf(p, dppf<0x121>(p));                                              \
    r = fmaxf(r, dppf<0x122>(r));                                                    \
    r = fmaxf(r, dppf<0x124>(r));                                                    \
    r = fmaxf(r, dppf<0x128>(r));                                                    \
    alpha = p * __builtin_amdgcn_rcpf(r);                                            \
    C += __logf(r);                                                                  \
    score += (tn == tag) ? m * (ltr[(prev << 4) | tag] + emit) : 0.f;                \
    last = upd ? tag : last;                                                         \
    prev = tag;                                                                      \
}

#define STEP8(pe, pt, pm)                                                            \
    STEP(pe, pt, pm, 0) STEP(pe, pt, pm, 1) STEP(pe, pt, pm, 2) STEP(pe, pt, pm, 3)  \
    STEP(pe, pt, pm, 4) STEP(pe, pt, pm, 5) STEP(pe, pt, pm, 6) STEP(pe, pt, pm, 7)

    LOADC(0, peA, ptA, pmA);
    LOADC(8, peB, ptB, pmB);

    // s = 0 init
    float alpha = __expf(st_raw + peA[0]);
    float C     = 0.f;
    const int tag0 = ptA[0];
    float score = (tn == tag0) ? (st_raw + peA[0]) : 0.f;
    int prev = tag0;
    int last = tag0;

    // s = 1..7 from chunk A
    STEP(peA, ptA, pmA, 1) STEP(peA, ptA, pmA, 2) STEP(peA, ptA, pmA, 3)
    STEP(peA, ptA, pmA, 4) STEP(peA, ptA, pmA, 5) STEP(peA, ptA, pmA, 6)
    STEP(peA, ptA, pmA, 7)

#pragma unroll 1
    for (int c = 2; c < 64; c += 2) {
        LOADC(c * 8, peA, ptA, pmA);          // prefetch chunk c
        STEP8(peB, ptB, pmB);                 // compute chunk c-1
        LOADC((c + 1) * 8, peB, ptB, pmB);    // prefetch chunk c+1
        STEP8(peA, ptA, pmA);                 // compute chunk c
    }
    STEP8(peB, ptB, pmB);                     // chunk 63 (s = 504..511)

    // end transition on the last-valid-tag lane
    score += (tn == last) ? et_raw : 0.f;

    // normalizer = C + log( sum_tn alpha[tn] * exp(end[tn]) )
    float v = alpha * e_end;
    v += dppf<0x121>(v); v += dppf<0x122>(v); v += dppf<0x124>(v); v += dppf<0x128>(v);
    const float norm = C + __logf(v);

    float ssum = score;
    ssum += dppf<0x121>(ssum); ssum += dppf<0x122>(ssum);
    ssum += dppf<0x124>(ssum); ssum += dppf<0x128>(ssum);

    if (tn == 0) out[b] = ssum - norm;
}

extern "C" void kernel_launch(void* const* d_in, const int* in_sizes, int n_in,
                              void* d_out, int out_size, void* d_ws, size_t ws_size,
                              hipStream_t stream) {
    const float* em = (const float*)d_in[0];
    const int*   tg = (const int*)  d_in[1];
    const float* mk = (const float*)d_in[2];
    const float* st = (const float*)d_in[3];
    const float* en = (const float*)d_in[4];
    const float* tr = (const float*)d_in[5];
    float* out = (float*)d_out;

    crf_fwd<<<(BATCH * NT) / 256, 256, 0, stream>>>(em, tg, mk, st, en, tr, out);
}

// Round 3
// 218.096 us; speedup vs baseline: 1.2591x; 1.2591x over previous
//
#include <hip/hip_runtime.h>

#define SEQ   512
#define BATCH 4096
#define NT    16
// fwd covers s=0..255, bwd covers s=256..511, combined via LDS.

template<int CTRL>
__device__ __forceinline__ float dppf(float x) {
    return __int_as_float(__builtin_amdgcn_update_dpp(0, __float_as_int(x), CTRL, 0xf, 0xf, true));
}
template<int CTRL>
__device__ __forceinline__ int dppi(int x) {
    return __builtin_amdgcn_update_dpp(0, x, CTRL, 0xf, 0xf, true);
}

// Block = 256 thr = 4 waves. wave&1: 0=fwd, 1=bwd. Each wave: 4 batch elems
// (16 lanes each, lane%16 = state tn). Block handles 8 batch elems; grid=512
// -> 2 blocks/CU -> 2 waves/SIMD (round-2 had 1/SIMD, VALUBusy 52%).
__global__ __launch_bounds__(256, 2) void crf_fb(
    const float* __restrict__ em,   // [S,B,T]
    const int*   __restrict__ tg,   // [S,B]
    const float* __restrict__ mk,   // [S,B]
    const float* __restrict__ st,   // [T]
    const float* __restrict__ en,   // [T]
    const float* __restrict__ tr,   // [T,T]
    float* __restrict__ out)        // [B]
{
    __shared__ float ltr[NT * NT];
    __shared__ float len[NT];
    __shared__ float s_vec[2][8][NT];
    __shared__ float s_C[2][8];
    __shared__ float s_sc[2][8];
    __shared__ int   s_last[2][8];
    __shared__ int   s_bv[8];

    const int tid = threadIdx.x;
    ltr[tid] = tr[tid];
    if (tid < NT) len[tid] = en[tid];
    __syncthreads();

    const int wave  = tid >> 6;
    const int lane  = tid & 63;
    const int half  = wave & 1;                     // 0 = fwd, 1 = bwd
    const int bslot = ((wave >> 1) << 2) | (lane >> 4);
    const int tn    = lane & 15;
    const int b     = blockIdx.x * 8 + bslot;

    // Runtime probe: does row_ror:1 deliver lane (i+1)&15's value or (i-1)&15's?
    const int pv = dppi<0x121>(lane);
    const bool plus = (pv == ((lane & ~15) | ((lane + 1) & 15)));

    // Rotated E = exp(trans) column/row so e[k] pairs with ror^k(src).
    // fwd: w[tn] = sum_tp a[tp]*E[tp][tn]  -> e[k] = E[rot_k(tn)][tn]
    // bwd: w[tn] = sum_j  u[j]*E[tn][j]    -> e[k] = E[tn][rot_k(tn)]
    float e[16];
#pragma unroll
    for (int k = 0; k < 16; ++k) {
        const int rk = plus ? ((tn + k) & 15) : ((tn - k) & 15);
        e[k] = __expf(half ? ltr[tn * NT + rk] : ltr[rk * NT + tn]);
    }
    const float st_raw = st[tn];

    const float* emp = em + b * NT + tn;
    const int*   tgp = tg + b;
    const float* mkp = mk + b;

    float peA[8], pmA[8], peB[8], pmB[8];
    int   ptA[9], ptB[9];

    float alpha, C = 0.f, score = 0.f;
    int last = 0, prev = 0, bv = 0;

#define MATVEC(src)                                                                  \
    const float a1  = dppf<0x121>(src), a2  = dppf<0x122>(src);                      \
    const float a3  = dppf<0x123>(src), a4  = dppf<0x124>(src);                      \
    const float a5  = dppf<0x125>(src), a6  = dppf<0x126>(src);                      \
    const float a7  = dppf<0x127>(src), a8  = dppf<0x128>(src);                      \
    const float a9  = dppf<0x129>(src), a10 = dppf<0x12A>(src);                      \
    const float a11 = dppf<0x12B>(src), a12 = dppf<0x12C>(src);                      \
    const float a13 = dppf<0x12D>(src), a14 = dppf<0x12E>(src);                      \
    const float a15 = dppf<0x12F>(src);                                              \
    float w0 = fmaf(src, e[0],  a4  * e[4]);                                         \
    float w1 = fmaf(a1,  e[1],  a5  * e[5]);                                         \
    float w2 = fmaf(a2,  e[2],  a6  * e[6]);                                         \
    float w3 = fmaf(a3,  e[3],  a7  * e[7]);                                         \
    w0 = fmaf(a8,  e[8],  w0); w1 = fmaf(a9,  e[9],  w1);                            \
    w2 = fmaf(a10, e[10], w2); w3 = fmaf(a11, e[11], w3);                            \
    w0 = fmaf(a12, e[12], w0); w1 = fmaf(a13, e[13], w1);                            \
    w2 = fmaf(a14, e[14], w2); w3 = fmaf(a15, e[15], w3);                            \
    const float w = (w0 + w1) + (w2 + w3);

#define RENORM {                                                                     \
    float r = fmaxf(alpha, dppf<0x121>(alpha));                                      \
    r = fmaxf(r, dppf<0x122>(r));                                                    \
    r = fmaxf(r, dppf<0x124>(r));                                                    \
    r = fmaxf(r, dppf<0x128>(r));                                                    \
    alpha = alpha * __builtin_amdgcn_rcpf(r);                                        \
    C += __logf(r);                                                                  \
}

#define FSTEP(pe, pt, pm, j) {                                                       \
    const float emit = pe[j]; const float m = pm[j]; const int tag = pt[j];          \
    MATVEC(alpha)                                                                    \
    const float p = w * __expf(emit);                                                \
    const bool upd = (m > 0.f);                                                      \
    alpha = upd ? p : alpha;                                                         \
    score += (tn == tag) ? m * (ltr[(prev << 4) | tag] + emit) : 0.f;                \
    last = upd ? tag : last;                                                         \
    prev = tag;                                                                      \
}

#define BSTEP(pe, pt9, pm, j) {                                                      \
    const float emit = pe[j]; const float m = pm[j];                                 \
    const int tag = pt9[j + 1]; const int tpv = pt9[j];                              \
    const float src = alpha * __expf(emit);                                          \
    MATVEC(src)                                                                      \
    const bool upd = (m > 0.f);                                                      \
    alpha = upd ? w : alpha;                                                         \
    score += (tn == tag) ? m * (ltr[(tpv << 4) | tag] + emit) : 0.f;                 \
    last = (upd && !bv) ? tag : last;                                                \
    bv = bv | (int)upd;                                                              \
}

#define FLOADC(s0, pe, pt, pm)                                   \
    { _Pragma("unroll")                                          \
      for (int j = 0; j < 8; ++j) {                              \
          pe[j] = emp[(s0 + j) * (BATCH * NT)];                  \
          pt[j] = tgp[(s0 + j) * BATCH];                         \
          pm[j] = mkp[(s0 + j) * BATCH];                         \
      } }

#define BLOADC(s0, pe, pt9, pm)                                  \
    { _Pragma("unroll")                                          \
      for (int j = 0; j < 8; ++j) {                              \
          pe[j]  = emp[(s0 + j) * (BATCH * NT)];                 \
          pm[j]  = mkp[(s0 + j) * BATCH];                        \
      }                                                          \
      _Pragma("unroll")                                          \
      for (int j = 0; j < 9; ++j)                                \
          pt9[j] = tgp[(s0 - 1 + j) * BATCH];                    \
    }

#define PROCF8(pe, pt, pm)                                       \
    FSTEP(pe, pt, pm, 0) FSTEP(pe, pt, pm, 1)                    \
    FSTEP(pe, pt, pm, 2) FSTEP(pe, pt, pm, 3) RENORM             \
    FSTEP(pe, pt, pm, 4) FSTEP(pe, pt, pm, 5)                    \
    FSTEP(pe, pt, pm, 6) FSTEP(pe, pt, pm, 7) RENORM

#define PROCB8(pe, pt9, pm)                                      \
    BSTEP(pe, pt9, pm, 7) BSTEP(pe, pt9, pm, 6)                  \
    BSTEP(pe, pt9, pm, 5) BSTEP(pe, pt9, pm, 4) RENORM           \
    BSTEP(pe, pt9, pm, 3) BSTEP(pe, pt9, pm, 2)                  \
    BSTEP(pe, pt9, pm, 1) BSTEP(pe, pt9, pm, 0) RENORM

    if (half == 0) {
        // ---------------- forward: s = 0 .. 255 ----------------
        FLOADC(0, peA, ptA, pmA);
        FLOADC(8, peB, ptB, pmB);
        alpha = __expf(st_raw + peA[0]);
        const int tag0 = ptA[0];
        score = (tn == tag0) ? (st_raw + peA[0]) : 0.f;
        prev = tag0; last = tag0;
        FSTEP(peA, ptA, pmA, 1) FSTEP(peA, ptA, pmA, 2)
        FSTEP(peA, ptA, pmA, 3) RENORM
        FSTEP(peA, ptA, pmA, 4) FSTEP(peA, ptA, pmA, 5)
        FSTEP(peA, ptA, pmA, 6) FSTEP(peA, ptA, pmA, 7) RENORM
#pragma unroll 1
        for (int c = 2; c <= 30; c += 2) {
            FLOADC(c * 8, peA, ptA, pmA);           // prefetch chunk c
            PROCF8(peB, ptB, pmB);                  // compute chunk c-1
            FLOADC((c + 1) * 8, peB, ptB, pmB);     // prefetch chunk c+1
            PROCF8(peA, ptA, pmA);                  // compute chunk c
        }
        PROCF8(peB, ptB, pmB);                      // chunk 31 (s=248..255)
    } else {
        // ---------------- backward: s = 511 .. 256 ----------------
        alpha = __expf(len[tn]);                    // gamma init = exp(end)
        BLOADC(256 + 31 * 8, peA, ptA, pmA);
        BLOADC(256 + 30 * 8, peB, ptB, pmB);
        PROCB8(peA, ptA, pmA);                      // chunk 31 (s=504..511)
#pragma unroll 1
        for (int k = 29; k >= 1; k -= 2) {
            BLOADC(256 + k * 8, peA, ptA, pmA);     // prefetch chunk k
            PROCB8(peB, ptB, pmB);                  // compute chunk k+1
            BLOADC(256 + (k - 1) * 8, peB, ptB, pmB);
            PROCB8(peA, ptA, pmA);                  // compute chunk k
        }
        PROCB8(peB, ptB, pmB);                      // chunk 0 (s=256..263)
    }

    // ---------------- publish & combine ----------------
    float sr = score;
    sr += dppf<0x121>(sr); sr += dppf<0x122>(sr);
    sr += dppf<0x124>(sr); sr += dppf<0x128>(sr);

    s_vec[half][bslot][tn] = alpha;
    if (tn == 0) {
        s_C[half][bslot]    = C;
        s_sc[half][bslot]   = sr;
        s_last[half][bslot] = last;
        if (half) s_bv[bslot] = bv;
    }
    __syncthreads();

    if (half == 0) {
        float v = alpha * s_vec[1][bslot][tn];      // alpha_mid * gamma_mid+1
        v += dppf<0x121>(v); v += dppf<0x122>(v);
        v += dppf<0x124>(v); v += dppf<0x128>(v);
        const float Z  = C + s_C[1][bslot] + __logf(v);
        const int   lt = s_bv[bslot] ? s_last[1][bslot] : last;
        const float sc = sr + s_sc[1][bslot] + len[lt];
        if (tn == 0) out[b] = sc - Z;
    }
}

extern "C" void kernel_launch(void* const* d_in, const int* in_sizes, int n_in,
                              void* d_out, int out_size, void* d_ws, size_t ws_size,
                              hipStream_t stream) {
    const float* em = (const float*)d_in[0];
    const int*   tg = (const int*)  d_in[1];
    const float* mk = (const float*)d_in[2];
    const float* st = (const float*)d_in[3];
    const float* en = (const float*)d_in[4];
    const float* tr = (const float*)d_in[5];
    float* out = (float*)d_out;

    crf_fb<<<BATCH / 8, 256, 0, stream>>>(em, tg, mk, st, en, tr, out);
}